// Round 5
// baseline (906.861 us; speedup 1.0000x reference)
//
#include <hip/hip_runtime.h>

#define N_TOK 8192
#define DM 1024
#define HID 4096
#define NE 8
#define MAX_TILES 144
#define MAX_SLOTS (MAX_TILES * 128)
#define LN_EPS 1e-5f

typedef __attribute__((ext_vector_type(8))) _Float16 f16x8;
typedef __attribute__((ext_vector_type(4))) _Float16 f16x4;
typedef __attribute__((ext_vector_type(4))) float f32x4;

// ---------------- workspace layout ----------------
// Wt1 region is dead after FFN1 -> Y (split-K part 0) aliases it.
// Xg region is dead after FFN1 -> Y1 (split-K part 1) aliases it.
constexpr size_t OFF_WT1 = 0;                                       // [E][HID][DM] f16
constexpr size_t OFF_WT2 = OFF_WT1 + (size_t)NE * HID * DM * 2;     // [E][DM][HID] f16
constexpr size_t OFF_XG  = OFF_WT2 + (size_t)NE * DM * HID * 2;     // [MAX_SLOTS][DM] f16
constexpr size_t OFF_H   = OFF_XG + (size_t)MAX_SLOTS * DM * 2;     // [MAX_SLOTS][HID] f16
constexpr size_t OFF_TOPI = OFF_H + (size_t)MAX_SLOTS * HID * 2;    // [N_TOK][2] i32
constexpr size_t OFF_TOPG = OFF_TOPI + (size_t)N_TOK * 2 * 4;       // [N_TOK][2] f32
constexpr size_t OFF_PTOK = OFF_TOPG + (size_t)N_TOK * 2 * 4;       // [MAX_SLOTS] i32
constexpr size_t OFF_SLOT = OFF_PTOK + (size_t)MAX_SLOTS * 4;       // [N_TOK][2] i32
constexpr size_t OFF_HDR = OFF_SLOT + (size_t)N_TOK * 2 * 4;        // header
constexpr size_t OFF_Y  = OFF_WT1;                                  // alias (dead after FFN1)
constexpr size_t OFF_Y1 = OFF_XG;                                   // alias (dead after FFN1)
constexpr size_t WS_NEEDED = OFF_HDR + 4096;                        // ~308 MiB
// header: [0..7] cnt, [8..15] imp(float), [16..23] cursor, [24..32] off,
//         [33] n_tiles(128-gran), [34..178) tile_expert

// gelu(v) = v * sigmoid(2c),  c = 0.79788456(v + 0.044715 v^3)
__device__ inline float gelu_fast(float v) {
  float c = 0.7978845608028654f * (v + 0.044715f * v * v * v);
  return v / (1.0f + __expf(-2.0f * c));
}

// async global->LDS, 16 B per lane. lds ptr must be wave-uniform.
__device__ inline void g2l16(const _Float16* g, _Float16* l) {
  __builtin_amdgcn_global_load_lds(
      (const __attribute__((address_space(1))) unsigned int*)g,
      (__attribute__((address_space(3))) unsigned int*)l, 16, 0, 0);
}

// stage one 256-row x 32-half (K=32) matrix part into a slot part.
// LDS layout: 128 virtual rows (vr = pair of K-32 rows) x 64 halves, chunk
// c' = parity*4 + kchunk, stored at c' ^ (vr&7) -- byte-identical access
// pattern to the r0-proven 128B-row swizzle (measured conflict-clean).
// Dest linear (global_load_lds rule); source pre-swizzled (both-sides rule).
__device__ inline void stage32(const _Float16* __restrict__ g, int ld,
                               _Float16* __restrict__ part, int tid) {
#pragma unroll
  for (int p = 0; p < 2; ++p) {
    int s = p * 512 + tid;
    int vr = s >> 3;
    int c7 = (s & 7) ^ (vr & 7);
    g2l16(g + (size_t)(2 * vr + (c7 >> 2)) * ld + (c7 & 3) * 8,
          part + (size_t)(p * 512 + (tid & 448)) * 8);
  }
}

// ---------------- router: fp64 logits, top-2, softmax stats ----------------
__global__ __launch_bounds__(256) void k_router(
    const float* __restrict__ x, const float* __restrict__ Wr,
    int* __restrict__ topi, float* __restrict__ topg,
    int* __restrict__ cnt, float* __restrict__ imp) {
  __shared__ float wr[NE * DM];          // 32 KB, [e][d] layout (conflict-free reads)
  __shared__ float blkImp[NE];
  __shared__ int blkCnt[NE];
  int tid = threadIdx.x;
  if (tid < NE) { blkImp[tid] = 0.0f; blkCnt[tid] = 0; }
  for (int i = tid; i < DM * NE; i += 256)
    wr[(i & 7) * DM + (i >> 3)] = Wr[i];   // Wr is [d][e]
  __syncthreads();
  int wave = tid >> 6, lane = tid & 63;
  for (int it = 0; it < 4; ++it) {
    int t = blockIdx.x * 16 + wave * 4 + it;
    double acc[NE];
#pragma unroll
    for (int e = 0; e < NE; ++e) acc[e] = 0.0;
    for (int j = 0; j < DM / 256; ++j) {
      int d = j * 256 + lane * 4;
      float4 xv = *(const float4*)(x + (size_t)t * DM + d);
#pragma unroll
      for (int e = 0; e < NE; ++e) {
        float4 wv = *(const float4*)(wr + e * DM + d);
        acc[e] += (double)xv.x * wv.x + (double)xv.y * wv.y +
                  (double)xv.z * wv.z + (double)xv.w * wv.w;
      }
    }
#pragma unroll
    for (int off = 32; off > 0; off >>= 1) {
#pragma unroll
      for (int e = 0; e < NE; ++e) acc[e] += __shfl_down(acc[e], off);
    }
    if (lane == 0) {
      int i0 = 0;
#pragma unroll
      for (int e = 1; e < NE; ++e) if (acc[e] > acc[i0]) i0 = e;
      int i1 = (i0 == 0) ? 1 : 0;
#pragma unroll
      for (int e = 0; e < NE; ++e) if (e != i0 && acc[e] > acc[i1]) i1 = e;
      double g0 = 1.0 / (1.0 + exp(acc[i1] - acc[i0]));
      topi[t * 2] = i0; topi[t * 2 + 1] = i1;
      topg[t * 2] = (float)g0; topg[t * 2 + 1] = (float)(1.0 - g0);
      atomicAdd(&blkCnt[i0], 1); atomicAdd(&blkCnt[i1], 1);
      double mx = acc[0];
#pragma unroll
      for (int e = 1; e < NE; ++e) mx = acc[e] > mx ? acc[e] : mx;
      double s = 0.0, p[NE];
#pragma unroll
      for (int e = 0; e < NE; ++e) { p[e] = exp(acc[e] - mx); s += p[e]; }
      double inv = 1.0 / s;
#pragma unroll
      for (int e = 0; e < NE; ++e) atomicAdd(&blkImp[e], (float)(p[e] * inv));
    }
  }
  __syncthreads();
  if (tid < NE) { atomicAdd(&cnt[tid], blkCnt[tid]); atomicAdd(&imp[tid], blkImp[tid]); }
}

// ---------------- setup: offsets (256-aligned), tile map, aux loss ----------------
__global__ void k_setup(int* __restrict__ hdr, float* __restrict__ aux_out) {
  int* cnt = hdr;
  float* imp = (float*)(hdr + 8);
  int* cursor = hdr + 16;
  int* off = hdr + 24;
  int* n_tiles_p = hdr + 33;
  int* tile_expert = hdr + 34;
  if (threadIdx.x == 0) {
    int offl[NE + 1];
    int o = 0;
    for (int e = 0; e < NE; ++e) {
      offl[e] = o; off[e] = o; cursor[e] = o;
      o += ((cnt[e] + 255) >> 8) << 8;    // 256-align so every 256-row M-tile is single-expert
    }
    offl[NE] = o; off[NE] = o;
    int nt = o >> 7;                       // 128-gran count (even)
    *n_tiles_p = nt;
    int e = 0;
    for (int i = 0; i < nt; ++i) {
      while (i * 128 >= offl[e + 1]) ++e;
      tile_expert[i] = e;
    }
    double a = 0.0;
    for (int e2 = 0; e2 < NE; ++e2)
      a += ((double)imp[e2] / (double)N_TOK) * ((double)cnt[e2] / (double)N_TOK);
    *aux_out = (float)((double)NE * a);
  }
}

__global__ __launch_bounds__(256) void k_init_pairs(int* __restrict__ pair_token) {
  int i = blockIdx.x * 256 + threadIdx.x;
  if (i < MAX_SLOTS) pair_token[i] = -1;
}

// ---------------- scatter token->slot ----------------
__global__ __launch_bounds__(256) void k_scatter(
    const int* __restrict__ topi, int* __restrict__ cursor,
    int* __restrict__ pair_token, int* __restrict__ slot_of) {
  int t = blockIdx.x * 256 + threadIdx.x;
#pragma unroll
  for (int k = 0; k < 2; ++k) {
    int e = topi[t * 2 + k];
    int p = atomicAdd(&cursor[e], 1);
    pair_token[p] = t;
    slot_of[t * 2 + k] = p;
  }
}

// ---------------- gather x rows (fp32 -> f16) ----------------
__global__ __launch_bounds__(256) void k_gather(
    const float* __restrict__ x, const int* __restrict__ pair_token,
    _Float16* __restrict__ Xg) {
  int slot = blockIdx.x;
  int t = pair_token[slot];
  int d = threadIdx.x * 4;
  f16x4 v4 = {0, 0, 0, 0};
  if (t >= 0) {
    float4 v = *(const float4*)(x + (size_t)t * DM + d);
    v4[0] = (_Float16)v.x; v4[1] = (_Float16)v.y;
    v4[2] = (_Float16)v.z; v4[3] = (_Float16)v.w;
  }
  *(f16x4*)(Xg + (size_t)slot * DM + d) = v4;
}

// ---------------- transpose + cast: fp32 [R][C] -> f16 [C][R], 64x64 tiles ----------------
__global__ __launch_bounds__(256) void k_transpose(
    const float* __restrict__ in, _Float16* __restrict__ out, int R, int C) {
  __shared__ float t[64 * 65];
  size_t base = (size_t)blockIdx.z * R * C;
  int c0 = blockIdx.x * 64, r0 = blockIdx.y * 64;
  int cx = (threadIdx.x & 15) * 4, ry = threadIdx.x >> 4;
#pragma unroll
  for (int p = 0; p < 4; ++p) {
    int r = p * 16 + ry;
    float4 v = *(const float4*)(in + base + (size_t)(r0 + r) * C + c0 + cx);
    t[r * 65 + cx] = v.x; t[r * 65 + cx + 1] = v.y;
    t[r * 65 + cx + 2] = v.z; t[r * 65 + cx + 3] = v.w;
  }
  __syncthreads();
#pragma unroll
  for (int q = 0; q < 2; ++q) {
    int lin = q * 256 + threadIdx.x;
    int c = lin >> 3, ch = lin & 7;
    f16x8 v;
#pragma unroll
    for (int j = 0; j < 8; ++j) v[j] = (_Float16)t[(ch * 8 + j) * 65 + c];
    *(f16x8*)(out + base + (size_t)(c0 + c) * R + r0 + ch * 8) = v;
  }
}

// ---------------- unified FFN GEMM: C = act(A @ Bw[e]^T + bias[e]) ----------------
// BM=BN=256, 8 waves (2M x 4N), per-wave 128x64 output (acc[8][4]).
// K pipelined in 32-wide half-steps over a 4-slot circular LDS buffer
// (4 x 32 KB = 128 KB): compute slot j while slots j+1,j+2 are in flight and
// slot j+3 is being issued -> counted s_waitcnt vmcnt(8) in steady state,
// vmcnt(4)/vmcnt(0) only in the 2-step tail (outstanding-count arithmetic:
// after issue at iter j, slots {j+1..min(j+3,NST-1)} are in flight, 4 loads
// each; landing slot j+1 needs vmcnt(4*(cnt-1))).
// T5 setprio around MFMA cluster; T1 bijective XCD-chunked grid swizzle.
// blockIdx.z = split-K part: K window [z*KD, z*KD+KD) of LDK; C0/C1 select.
template <int KD, int LDK, int ND, bool GELU>
__global__ __launch_bounds__(512, 2) void k_ffn(
    const _Float16* __restrict__ A, const _Float16* __restrict__ Bw,
    const float* __restrict__ bias, _Float16* __restrict__ C0,
    _Float16* __restrict__ C1, const int* __restrict__ hdr) {
  constexpr int GX = ND / 256;
  constexpr int NWG = GX * (MAX_TILES / 2);
  constexpr int Q = NWG >> 3, R = NWG & 7;
  constexpr int NST = KD / 32;
  constexpr int SLOT = 256 * 64;         // halves: A(128vr x 64) + B(128vr x 64)
  int orig = blockIdx.y * GX + blockIdx.x;
  int xcd = orig & 7, loc = orig >> 3;
  int wg = (xcd < R ? xcd * (Q + 1) : R * (Q + 1) + (xcd - R) * Q) + loc;
  int tileM = wg / GX, tileN = wg % GX;
  if (tileM * 2 >= hdr[33]) return;
  int e = hdr[34 + tileM * 2];
  __shared__ _Float16 lds[4 * SLOT];     // 128 KB
  int tid = threadIdx.x;
  int wave = tid >> 6, lane = tid & 63;
  int wm = wave >> 2, wn = wave & 3;
  int l16 = lane & 15, quad = lane >> 4;
  const _Float16* Ag = A + (size_t)tileM * 256 * LDK + (size_t)blockIdx.z * KD;
  const _Float16* Bg = Bw + (size_t)e * ND * LDK + (size_t)tileN * 256 * LDK +
                       (size_t)blockIdx.z * KD;

  // fragment LDS offsets (halves): row r -> vrow r>>1, chunk c = (r&1)*4+quad, XOR vr&7
  int aoff[8], boff[4];
#pragma unroll
  for (int mi = 0; mi < 8; ++mi) {
    int r = wm * 128 + mi * 16 + l16;
    int v = r >> 1, c = ((r & 1) << 2) | quad;
    aoff[mi] = v * 64 + ((c ^ (v & 7)) << 3);
  }
#pragma unroll
  for (int ni = 0; ni < 4; ++ni) {
    int r = wn * 64 + ni * 16 + l16;
    int v = r >> 1, c = ((r & 1) << 2) | quad;
    boff[ni] = 8192 + v * 64 + ((c ^ (v & 7)) << 3);
  }

  f32x4 acc[8][4];
  const f32x4 fz = {0.f, 0.f, 0.f, 0.f};
#pragma unroll
  for (int a = 0; a < 8; ++a)
#pragma unroll
    for (int b = 0; b < 4; ++b) acc[a][b] = fz;

  // prologue: issue slots 0,1,2 (12 loads/thread); wait slot 0 (<=8 outstanding)
#pragma unroll
  for (int jj = 0; jj < 3; ++jj) {
    stage32(Ag + jj * 32, LDK, lds + jj * SLOT, tid);
    stage32(Bg + jj * 32, LDK, lds + jj * SLOT + 8192, tid);
  }
  asm volatile("s_waitcnt vmcnt(8)" ::: "memory");
  __builtin_amdgcn_s_barrier();

#pragma unroll 1
  for (int j = 0; j < NST; ++j) {
    __builtin_amdgcn_sched_barrier(0);
    const _Float16* sl = lds + (j & 3) * SLOT;
    f16x8 af[8], bf[4];
#pragma unroll
    for (int mi = 0; mi < 8; ++mi) af[mi] = *(const f16x8*)(sl + aoff[mi]);
#pragma unroll
    for (int ni = 0; ni < 4; ++ni) bf[ni] = *(const f16x8*)(sl + boff[ni]);
    if (j + 3 < NST) {                    // slot (j+3)&3 = (j-1)&3: readers done last iter
      _Float16* dst = lds + ((j + 3) & 3) * SLOT;
      stage32(Ag + (j + 3) * 32, LDK, dst, tid);
      stage32(Bg + (j + 3) * 32, LDK, dst + 8192, tid);
    }
    __builtin_amdgcn_s_setprio(1);
#pragma unroll
    for (int mi = 0; mi < 8; ++mi)
#pragma unroll
      for (int ni = 0; ni < 4; ++ni)
        acc[mi][ni] = __builtin_amdgcn_mfma_f32_16x16x32_f16(af[mi], bf[ni], acc[mi][ni], 0, 0, 0);
    __builtin_amdgcn_s_setprio(0);
    asm volatile("s_waitcnt lgkmcnt(0)" ::: "memory");   // ds_reads done before slot reuse
    __builtin_amdgcn_sched_barrier(0);
    if (j < NST - 3)       asm volatile("s_waitcnt vmcnt(8)" ::: "memory");  // slot j+1 landed
    else if (j == NST - 3) asm volatile("s_waitcnt vmcnt(4)" ::: "memory");
    else                   asm volatile("s_waitcnt vmcnt(0)" ::: "memory");
    __builtin_amdgcn_sched_barrier(0);
    __builtin_amdgcn_s_barrier();
  }

  // epilogue: bias (+gelu) -> per-wave LDS scratch (two 64-row halves) -> f16x8 stores
  int rowBase = tileM * 256 + wm * 128;
  int colBase = tileN * 256 + wn * 64;
  _Float16* Cout = blockIdx.z ? C1 : C0;
  float bscale = blockIdx.z ? 0.f : 1.f;
  _Float16* sc = lds + wave * 4096;      // 8 KB per wave
  float bv[4];
#pragma unroll
  for (int ni = 0; ni < 4; ++ni)
    bv[ni] = bscale * bias[e * ND + colBase + ni * 16 + l16];
#pragma unroll
  for (int h = 0; h < 2; ++h) {
#pragma unroll
    for (int mi = 0; mi < 4; ++mi)
#pragma unroll
      for (int ni = 0; ni < 4; ++ni)
#pragma unroll
        for (int i = 0; i < 4; ++i) {
          int rr = mi * 16 + quad * 4 + i;
          int c2 = ni * 16 + l16;
          float v = acc[h * 4 + mi][ni][i] + bv[ni];
          sc[rr * 64 + c2] = (_Float16)(GELU ? gelu_fast(v) : v);
        }
    __syncthreads();
#pragma unroll
    for (int jj = 0; jj < 8; ++jj) {
      int lin = jj * 64 + lane;
      int rr = lin >> 3, ch = lin & 7;
      f16x8 v = *(const f16x8*)(sc + rr * 64 + ch * 8);
      *(f16x8*)(Cout + (size_t)(rowBase + h * 64 + rr) * ND + colBase + ch * 8) = v;
    }
    __syncthreads();
  }
}

// ---------------- combine (split-K partials) + residual + LayerNorm ----------------
__global__ __launch_bounds__(256) void k_ln(
    const float* __restrict__ x, const _Float16* __restrict__ Y,
    const _Float16* __restrict__ Y1,
    const int* __restrict__ slot_of, const float* __restrict__ topg,
    const float* __restrict__ lnw, const float* __restrict__ lnb,
    float* __restrict__ out) {
  int t = blockIdx.x, tid = threadIdx.x;
  int s0 = slot_of[t * 2], s1 = slot_of[t * 2 + 1];
  float g0 = topg[t * 2], g1 = topg[t * 2 + 1];
  float4 xv = ((const float4*)(x + (size_t)t * DM))[tid];
  f16x4 y0 = ((const f16x4*)(Y + (size_t)s0 * DM))[tid];
  f16x4 y1 = ((const f16x4*)(Y + (size_t)s1 * DM))[tid];
  f16x4 z0 = ((const f16x4*)(Y1 + (size_t)s0 * DM))[tid];
  f16x4 z1 = ((const f16x4*)(Y1 + (size_t)s1 * DM))[tid];
  float a0 = (float)y0[0] + (float)z0[0], a1 = (float)y0[1] + (float)z0[1];
  float a2 = (float)y0[2] + (float)z0[2], a3 = (float)y0[3] + (float)z0[3];
  float b0 = (float)y1[0] + (float)z1[0], b1v = (float)y1[1] + (float)z1[1];
  float b2v = (float)y1[2] + (float)z1[2], b3 = (float)y1[3] + (float)z1[3];
  float r0 = xv.x + g0 * a0 + g1 * b0;
  float r1 = xv.y + g0 * a1 + g1 * b1v;
  float r2 = xv.z + g0 * a2 + g1 * b2v;
  float r3 = xv.w + g0 * a3 + g1 * b3;
  float s = r0 + r1 + r2 + r3;
  float s2 = r0 * r0 + r1 * r1 + r2 * r2 + r3 * r3;
#pragma unroll
  for (int off = 32; off > 0; off >>= 1) {
    s += __shfl_down(s, off);
    s2 += __shfl_down(s2, off);
  }
  __shared__ float ss[4], ss2[4];
  int wave = tid >> 6, lane = tid & 63;
  if (lane == 0) { ss[wave] = s; ss2[wave] = s2; }
  __syncthreads();
  float S = ss[0] + ss[1] + ss[2] + ss[3];
  float S2 = ss2[0] + ss2[1] + ss2[2] + ss2[3];
  float mu = S * (1.0f / DM);
  float var = S2 * (1.0f / DM) - mu * mu;
  float inv = rsqrtf(var + LN_EPS);
  float4 wv = ((const float4*)lnw)[tid];
  float4 bv = ((const float4*)lnb)[tid];
  float4 o;
  o.x = (r0 - mu) * inv * wv.x + bv.x;
  o.y = (r1 - mu) * inv * wv.y + bv.y;
  o.z = (r2 - mu) * inv * wv.z + bv.z;
  o.w = (r3 - mu) * inv * wv.w + bv.w;
  ((float4*)(out + (size_t)t * DM))[tid] = o;
}

// sentinel: encodes ws_size (MB) into absmax if workspace is too small
__global__ void k_sentinel(float* out, float v) { out[threadIdx.x] = v; }

extern "C" void kernel_launch(void* const* d_in, const int* in_sizes, int n_in,
                              void* d_out, int out_size, void* d_ws, size_t ws_size,
                              hipStream_t stream) {
  const float* x = (const float*)d_in[0];
  const float* Wr = (const float*)d_in[1];
  const float* W1 = (const float*)d_in[2];
  const float* b1 = (const float*)d_in[3];
  const float* W2 = (const float*)d_in[4];
  const float* b2 = (const float*)d_in[5];
  const float* lnw = (const float*)d_in[6];
  const float* lnb = (const float*)d_in[7];
  float* out = (float*)d_out;
  char* ws = (char*)d_ws;

  if (ws_size < WS_NEEDED) {
    k_sentinel<<<1, 256, 0, stream>>>(out, 1.0e6f + (float)(ws_size >> 20));
    return;
  }

  _Float16* Wt1 = (_Float16*)(ws + OFF_WT1);
  _Float16* Wt2 = (_Float16*)(ws + OFF_WT2);
  _Float16* Xg = (_Float16*)(ws + OFF_XG);
  _Float16* Hbuf = (_Float16*)(ws + OFF_H);
  _Float16* Ybuf = (_Float16*)(ws + OFF_Y);    // aliases Wt1 (dead after FFN1)
  _Float16* Ybuf1 = (_Float16*)(ws + OFF_Y1);  // aliases Xg  (dead after FFN1)
  int* topi = (int*)(ws + OFF_TOPI);
  float* topg = (float*)(ws + OFF_TOPG);
  int* pair_token = (int*)(ws + OFF_PTOK);
  int* slot_of = (int*)(ws + OFF_SLOT);
  int* hdr = (int*)(ws + OFF_HDR);
  int* cnt = hdr;
  float* imp = (float*)(hdr + 8);
  int* cursor = hdr + 16;

  hipMemsetAsync(hdr, 0, 64, stream);  // cnt + imp

  k_transpose<<<dim3(HID / 64, DM / 64, NE), 256, 0, stream>>>(W1, Wt1, DM, HID);
  k_transpose<<<dim3(DM / 64, HID / 64, NE), 256, 0, stream>>>(W2, Wt2, HID, DM);
  k_router<<<512, 256, 0, stream>>>(x, Wr, topi, topg, cnt, imp);
  k_setup<<<1, 1, 0, stream>>>(hdr, out + (size_t)N_TOK * DM);
  k_init_pairs<<<(MAX_SLOTS + 255) / 256, 256, 0, stream>>>(pair_token);
  k_scatter<<<N_TOK / 256, 256, 0, stream>>>(topi, cursor, pair_token, slot_of);
  k_gather<<<MAX_SLOTS, 256, 0, stream>>>(x, pair_token, Xg);
  k_ffn<DM, DM, HID, true><<<dim3(HID / 256, MAX_TILES / 2, 1), 512, 0, stream>>>(
      Xg, Wt1, b1, Hbuf, Hbuf, hdr);
  // split-K=2 over HID: part z reads K-window [z*2048, +2048); partials -> Ybuf/Ybuf1
  k_ffn<HID / 2, HID, DM, false><<<dim3(DM / 256, MAX_TILES / 2, 2), 512, 0, stream>>>(
      Hbuf, Wt2, b2, Ybuf, Ybuf1, hdr);
  k_ln<<<N_TOK, 256, 0, stream>>>(x, Ybuf, Ybuf1, slot_of, topg, lnw, lnb, out);
}